// Round 11
// baseline (246.466 us; speedup 1.0000x reference)
//
#include <hip/hip_runtime.h>

#define WID 256
#define EPS_GN 1e-5f

typedef __bf16 v8bf __attribute__((ext_vector_type(8)));
typedef __bf16 v2bf __attribute__((ext_vector_type(2)));
typedef float  v4f  __attribute__((ext_vector_type(4)));

__device__ inline unsigned short f2b(float f) {
    unsigned int u = __builtin_bit_cast(unsigned int, f);
    unsigned int r = (u + 0x7fffu + ((u >> 16) & 1u)) >> 16;
    return (unsigned short)r;
}
__device__ inline __bf16 f2bf(float f) {
    unsigned short s = f2b(f);
    return __builtin_bit_cast(__bf16, s);
}
__device__ inline float lo16(unsigned int u) { return __builtin_bit_cast(float, u << 16); }
__device__ inline float hi16(unsigned int u) { return __builtin_bit_cast(float, u & 0xffff0000u); }

#if __has_builtin(__builtin_amdgcn_cvt_pk_bf16_f32)
__device__ inline unsigned int pkbf(float a, float b) {
    v2bf r = __builtin_amdgcn_cvt_pk_bf16_f32(a, b);
    return __builtin_bit_cast(unsigned int, r);
}
#else
__device__ inline unsigned int pkbf(float a, float b) {
    return (unsigned int)f2b(a) | ((unsigned int)f2b(b) << 16);
}
#endif

#if __has_builtin(__builtin_amdgcn_fdot2_f32_bf16)
__device__ inline float pairsum(unsigned int u, float s) {
    v2bf p = __builtin_bit_cast(v2bf, u);
    v2bf ones = __builtin_bit_cast(v2bf, 0x3f803f80u);
    return __builtin_amdgcn_fdot2_f32_bf16(p, ones, s, false);
}
#else
__device__ inline float pairsum(unsigned int u, float s) {
    return s + lo16(u) + hi16(u);
}
#endif

// load 8 consecutive fp32 and round to a bf16x8 fragment
__device__ inline v8bf ld_w8(const float* __restrict__ p) {
    float4 a = *(const float4*)p, b = *(const float4*)(p + 4);
    unsigned int u0 = pkbf(a.x, a.y), u1 = pkbf(a.z, a.w);
    unsigned int u2 = pkbf(b.x, b.y), u3 = pkbf(b.z, b.w);
    uint4 pk = make_uint4(u0, u1, u2, u3);
    return __builtin_bit_cast(v8bf, pk);
}

// ================= prep + proj fused =================
__global__ __launch_bounds__(256, 2)
void prepproj_k(const float* __restrict__ x, const float* __restrict__ Wsrc,
                const float* __restrict__ Wtgt, const float* __restrict__ Wp,
                const float* __restrict__ Wg, const float* __restrict__ Wv,
                const float* __restrict__ emb, const int* __restrict__ eidx,
                unsigned short* __restrict__ xsb, unsigned short* __restrict__ xtb,
                unsigned short* __restrict__ Wpb, unsigned short* __restrict__ Wgb,
                unsigned short* __restrict__ Wvb, unsigned short* __restrict__ embWgT,
                int* __restrict__ cnt, float* __restrict__ aggact,
                int N, int E, int BOND, int PB, int AUX) {
    __shared__ unsigned short ab[32 * 264];
    int t = threadIdx.x, b = blockIdx.x;

    if (b >= PB) {
        int atid = (b - PB) * 256 + t, asz = AUX * 256;
        for (int i = atid; i < 65536; i += asz) Wpb[i] = f2b(Wp[i]);
        for (int i = atid; i < 8192; i += asz) { Wgb[i] = f2b(Wg[i]); Wvb[i] = f2b(Wv[i]); }
        for (int i = atid; i < 16384; i += asz) {
            int j = i >> 6, k = i & 63;
            float sacc = 0.f;
            if (k < BOND) {
                int h = j >> 5, f = j & 31;
                const float* er = emb + (size_t)k * WID + h * 32;
                const float* wr = Wg + h * 1024 + f * 32;
#pragma unroll
                for (int d = 0; d < 32; d++) sacc += er[d] * wr[d];
            }
            embWgT[j * 64 + k] = f2b(sacc);
        }
        {
            float4* ap = (float4*)aggact;
            int n4 = (N * WID) >> 2;
            for (int i = atid; i < n4; i += asz) ap[i] = make_float4(0.f, 0.f, 0.f, 0.f);
        }
        for (int i = atid; i < E; i += asz) atomicAdd(&cnt[eidx[E + i]], 1);
        return;
    }

    // ---- proj tile ----
    int n0 = b * 32;
#pragma unroll
    for (int ch = 0; ch < 8; ch++) {
        int flat = ch * 1024 + t * 4;
        int row = flat >> 8, col = flat & 255;
        int n = n0 + row;
        float4 v = (n < N) ? *(const float4*)&x[(size_t)n * WID + col]
                           : make_float4(0.f, 0.f, 0.f, 0.f);
        *(uint2*)&ab[row * 264 + col] = make_uint2(pkbf(v.x, v.y), pkbf(v.z, v.w));
    }
    __syncthreads();
    int w = t >> 6, lane = t & 63, m = lane & 15, kg = lane >> 4;
#pragma unroll
    for (int pass = 0; pass < 2; pass++) {
        const float* Wf = pass ? Wtgt : Wsrc;
        unsigned short* outp = pass ? xtb : xsb;
        v4f acc[2][4];
#pragma unroll
        for (int mt = 0; mt < 2; mt++)
#pragma unroll
            for (int nt = 0; nt < 4; nt++) acc[mt][nt] = (v4f){0.f, 0.f, 0.f, 0.f};
#pragma unroll
        for (int kt = 0; kt < 8; kt++) {
            int k0 = kt * 32 + kg * 8;
            v8bf a0 = *(const v8bf*)&ab[m * 264 + k0];
            v8bf a1 = *(const v8bf*)&ab[(16 + m) * 264 + k0];
#pragma unroll
            for (int nt = 0; nt < 4; nt++) {
                int j = w * 64 + nt * 16 + m;
                v8bf bfr = ld_w8(&Wf[j * 256 + k0]);
                acc[0][nt] = __builtin_amdgcn_mfma_f32_16x16x32_bf16(a0, bfr, acc[0][nt], 0, 0, 0);
                acc[1][nt] = __builtin_amdgcn_mfma_f32_16x16x32_bf16(a1, bfr, acc[1][nt], 0, 0, 0);
            }
        }
#pragma unroll
        for (int mt = 0; mt < 2; mt++)
#pragma unroll
            for (int r = 0; r < 4; r++) {
                int n = n0 + mt * 16 + kg * 4 + r;
                if (n < N)
#pragma unroll
                    for (int nt = 0; nt < 4; nt++)
                        outp[(size_t)n * WID + w * 64 + nt * 16 + m] = f2b(acc[mt][nt][r]);
            }
    }
}

// ================= exclusive scan (LDS-staged, coalesced) =================
__global__ void scan_k(const int* __restrict__ cnt, int* __restrict__ cur, int N) {
    __shared__ int buf[10240];
    __shared__ int part[1024];
    int t = threadIdx.x;
    int C = (N + 1023) >> 10;           // N <= 10240
    int M = C << 10;
    for (int i = t; i < M; i += 1024) buf[i] = (i < N) ? cnt[i] : 0;
    __syncthreads();
    int base0 = t * C;
    int s = 0;
    for (int i = 0; i < C; i++) s += buf[base0 + i];
    part[t] = s;
    __syncthreads();
    for (int d = 1; d < 1024; d <<= 1) {
        int v = (t >= d) ? part[t - d] : 0;
        __syncthreads();
        part[t] += v;
        __syncthreads();
    }
    int base = (t == 0) ? 0 : part[t - 1];
    for (int i = 0; i < C; i++) {
        int idx = base0 + i;
        int v = buf[idx];
        buf[idx] = base;
        base += v;
    }
    __syncthreads();
    for (int i = t; i < N; i += 1024) cur[i] = buf[i];
}

// ================= scatter perm =================
__global__ void scat_k(const int* __restrict__ eidx, int* __restrict__ cur,
                       int* __restrict__ perm, int E) {
    int i = blockIdx.x * 256 + threadIdx.x;
    if (i < E) { int p = atomicAdd(&cur[eidx[E + i]], 1); perm[p] = i; }
}

// ================= fused edge pipeline (register-resident xn) =================
__global__ __launch_bounds__(256, 6)
void edge_k(const unsigned short* __restrict__ xsb, const unsigned short* __restrict__ xtb,
            const int* __restrict__ eidx, const int* __restrict__ eattr,
            const int* __restrict__ perm, const unsigned short* __restrict__ Wgb,
            const unsigned short* __restrict__ Wvb, const unsigned short* __restrict__ embWgT,
            float* __restrict__ aggact, int E, int NT, int PER) {
    __shared__ unsigned short actb[256 * 34];  // act_t[col][e], stride 34
    __shared__ unsigned short Mld[32 * 72];
    __shared__ int src_s[32], tgt_s[32];
    __shared__ int segmask_s;

    // XCD-aware swizzle over sorted tiles
    int tile = (blockIdx.x & 7) * PER + (blockIdx.x >> 3);
    if (tile >= NT) return;
    int t = threadIdx.x;
    int e0 = tile * 32;
    int ne = min(32, E - e0);

    // init: indices, M rows, segment flush bitmask (wave 0)
    {
        int tgtv = -1;
        if (t < 32) {
            int p = (t < ne) ? perm[e0 + t] : -1;
            src_s[t] = (p >= 0) ? eidx[p] : 0;
            tgtv = (p >= 0) ? eidx[E + p] : -1;
            tgt_s[t] = (tgtv >= 0) ? tgtv : 0;
            int a0 = 0, a1 = 0, a2 = 0;
            if (p >= 0) {
                const int* ap = eattr + (size_t)p * 3;
                a0 = ap[0]; a1 = ap[1]; a2 = ap[2];
            }
            unsigned int* Mr = (unsigned int*)&Mld[t * 72];
#pragma unroll
            for (int q = 0; q < 32; q++) Mr[q] = 0;
            int c = (a0 != 0) + (a1 != 0) + (a2 != 0);
            float inv = (p >= 0 && c > 0) ? 1.f / (float)c : 0.f;
            float wa = inv * (float)(1 + (a1 == a0) + (a2 == a0));
            float wb = inv * (float)(1 + (a2 == a1));
            Mld[t * 72 + a0] = f2b(wa);
            if (a1 != a0) Mld[t * 72 + a1] = f2b(wb);
            if (a2 != a0 && a2 != a1) Mld[t * 72 + a2] = f2b(inv);
        }
        if (t < 64) {
            int nxt = __shfl_down(tgtv, 1);
            bool flag = (t < ne) && ((t == ne - 1) || (nxt != tgtv));
            unsigned long long bal = __ballot(flag);
            if (t == 0) segmask_s = (int)(unsigned int)bal;
        }
    }
    __syncthreads();

    int w = t >> 6, lane = t & 63, m = lane & 15, kg = lane >> 4;

    // P1: per-lane direct gather of this lane's A-fragment columns + GN via kg-butterfly
    v8bf axn[2][2];   // [hh][mt]
#pragma unroll
    for (int mt = 0; mt < 2; mt++) {
        int e = mt * 16 + m;
        bool live = (e < ne);
        const unsigned short* prs = xsb + (size_t)src_s[e] * WID;
        const unsigned short* prt = xtb + (size_t)tgt_s[e] * WID;
#pragma unroll
        for (int hh = 0; hh < 2; hh++) {
            int col = (w * 2 + hh) * 32 + kg * 8;
            uint4 us = *(const uint4*)(prs + col);
            uint4 ut = *(const uint4*)(prt + col);
            const unsigned int* au = (const unsigned int*)&us;
            const unsigned int* bu = (const unsigned int*)&ut;
            float v[8];
            float s = 0.f, q = 0.f;
#pragma unroll
            for (int qq = 0; qq < 4; qq++) {
                float x0 = lo16(au[qq]) + lo16(bu[qq]);
                float x1 = hi16(au[qq]) + hi16(bu[qq]);
                if (!live) { x0 = 0.f; x1 = 0.f; }
                v[2 * qq] = x0; v[2 * qq + 1] = x1;
                s += x0 + x1;
                q += x0 * x0 + x1 * x1;
            }
            // reduce across the 4 kg-lanes sharing this (e, head)
            s += __shfl_xor(s, 16); q += __shfl_xor(q, 16);
            s += __shfl_xor(s, 32); q += __shfl_xor(q, 32);
            float mu = s * (1.f / 32.f);
            float var = q * (1.f / 32.f) - mu * mu;
            float rs = rsqrtf(var + EPS_GN);
            float nmr = -mu * rs;
            uint4 pk = make_uint4(
                pkbf(fmaf(v[0], rs, nmr), fmaf(v[1], rs, nmr)),
                pkbf(fmaf(v[2], rs, nmr), fmaf(v[3], rs, nmr)),
                pkbf(fmaf(v[4], rs, nmr), fmaf(v[5], rs, nmr)),
                pkbf(fmaf(v[6], rs, nmr), fmaf(v[7], rs, nmr)));
            axn[hh][mt] = __builtin_bit_cast(v8bf, pk);
        }
    }

    // P5: gate/val MFMA -> act transposed into actb (no barrier needed before: Mld synced at init)
    {
        v8bf aM[2][2];
#pragma unroll
        for (int mt = 0; mt < 2; mt++) {
            int row = mt * 16 + m;
            aM[mt][0] = *(const v8bf*)&Mld[row * 72 + kg * 8];
            aM[mt][1] = *(const v8bf*)&Mld[row * 72 + 32 + kg * 8];
        }
        v4f z = {0.f, 0.f, 0.f, 0.f};
#pragma unroll
        for (int hh = 0; hh < 2; hh++) {
            int h = w * 2 + hh;
#pragma unroll
            for (int nt = 0; nt < 2; nt++) {
                int fj = nt * 16 + m;
                int j = h * 32 + fj;
                v8bf bWg = *(const v8bf*)&Wgb[h * 1024 + fj * 32 + kg * 8];
                v8bf bWv = *(const v8bf*)&Wvb[h * 1024 + fj * 32 + kg * 8];
                v8bf bE0 = *(const v8bf*)&embWgT[j * 64 + kg * 8];
                v8bf bE1 = *(const v8bf*)&embWgT[j * 64 + 32 + kg * 8];
#pragma unroll
                for (int mt = 0; mt < 2; mt++) {
                    v4f cgm = __builtin_amdgcn_mfma_f32_16x16x32_bf16(axn[hh][mt], bWg, z, 0, 0, 0);
                    cgm = __builtin_amdgcn_mfma_f32_16x16x32_bf16(aM[mt][0], bE0, cgm, 0, 0, 0);
                    cgm = __builtin_amdgcn_mfma_f32_16x16x32_bf16(aM[mt][1], bE1, cgm, 0, 0, 0);
                    v4f cv = __builtin_amdgcn_mfma_f32_16x16x32_bf16(axn[hh][mt], bWv, z, 0, 0, 0);
                    float a0 = fmaxf(cgm[0], 0.f) * cv[0];
                    float a1 = fmaxf(cgm[1], 0.f) * cv[1];
                    float a2 = fmaxf(cgm[2], 0.f) * cv[2];
                    float a3 = fmaxf(cgm[3], 0.f) * cv[3];
                    int e0i = mt * 16 + kg * 4;
                    *(unsigned int*)&actb[j * 34 + e0i]     = pkbf(a0, a1);
                    *(unsigned int*)&actb[j * 34 + e0i + 2] = pkbf(a2, a3);
                }
            }
        }
    }
    __syncthreads();

    // P6: segmented column reduce; packed pair-sums, scalar bit-test flushes
    {
        unsigned int mask = (unsigned int)__builtin_amdgcn_readfirstlane(segmask_s);
        float sum = 0.f;
#pragma unroll
        for (int i = 0; i < 16; i++) {
            unsigned int r = *(const unsigned int*)&actb[t * 34 + 2 * i];
            if (!((mask >> (2 * i)) & 1)) {
                sum = pairsum(r, sum);
                if ((mask >> (2 * i + 1)) & 1) {
                    int tg = __builtin_amdgcn_readfirstlane(tgt_s[2 * i + 1]);
                    atomicAdd(&aggact[(size_t)tg * WID + t], sum);
                    sum = 0.f;
                }
            } else {
                sum += lo16(r);
                int tg = __builtin_amdgcn_readfirstlane(tgt_s[2 * i]);
                atomicAdd(&aggact[(size_t)tg * WID + t], sum);
                sum = hi16(r);
                if ((mask >> (2 * i + 1)) & 1) {
                    int tg2 = __builtin_amdgcn_readfirstlane(tgt_s[2 * i + 1]);
                    atomicAdd(&aggact[(size_t)tg2 * WID + t], sum);
                    sum = 0.f;
                }
            }
        }
    }
}

// ================= post: out = deg^p ⊙ (aggact @ Wp^T) =================
__global__ __launch_bounds__(256, 2)
void post_k(const float* __restrict__ aggact, const unsigned short* __restrict__ Wpb,
            const float* __restrict__ deg, const float* __restrict__ dp,
            float* __restrict__ out, int N) {
    __shared__ unsigned short ab[32 * 264];
    __shared__ float degl[32];
    int t = threadIdx.x;
    int n0 = blockIdx.x * 32;
#pragma unroll
    for (int ch = 0; ch < 8; ch++) {
        int flat = ch * 1024 + t * 4;
        int row = flat >> 8, col = flat & 255;
        int n = n0 + row;
        float4 v = (n < N) ? *(const float4*)&aggact[(size_t)n * WID + col]
                           : make_float4(0.f, 0.f, 0.f, 0.f);
        *(uint2*)&ab[row * 264 + col] = make_uint2(pkbf(v.x, v.y), pkbf(v.z, v.w));
    }
    if (t < 32) {
        int n = n0 + t;
        degl[t] = (n < N) ? log2f(deg[n]) : 0.f;
    }
    __syncthreads();
    int w = t >> 6, lane = t & 63, m = lane & 15, kg = lane >> 4;
    v4f acc[2][4];
#pragma unroll
    for (int mt = 0; mt < 2; mt++)
#pragma unroll
        for (int nt = 0; nt < 4; nt++) acc[mt][nt] = (v4f){0.f, 0.f, 0.f, 0.f};
#pragma unroll
    for (int kt = 0; kt < 8; kt++) {
        int k0 = kt * 32 + kg * 8;
        v8bf a0 = *(const v8bf*)&ab[m * 264 + k0];
        v8bf a1 = *(const v8bf*)&ab[(16 + m) * 264 + k0];
#pragma unroll
        for (int nt = 0; nt < 4; nt++) {
            int j = w * 64 + nt * 16 + m;
            v8bf b = *(const v8bf*)&Wpb[j * 256 + k0];
            acc[0][nt] = __builtin_amdgcn_mfma_f32_16x16x32_bf16(a0, b, acc[0][nt], 0, 0, 0);
            acc[1][nt] = __builtin_amdgcn_mfma_f32_16x16x32_bf16(a1, b, acc[1][nt], 0, 0, 0);
        }
    }
    float dpv[4];
#pragma unroll
    for (int nt = 0; nt < 4; nt++) dpv[nt] = dp[w * 64 + nt * 16 + m];
#pragma unroll
    for (int mt = 0; mt < 2; mt++)
#pragma unroll
        for (int r = 0; r < 4; r++) {
            int row = mt * 16 + kg * 4 + r;
            int n = n0 + row;
            if (n < N) {
                float ld = degl[row];
#pragma unroll
                for (int nt = 0; nt < 4; nt++)
                    out[(size_t)n * WID + w * 64 + nt * 16 + m] =
                        exp2f(dpv[nt] * ld) * acc[mt][nt][r];
            }
        }
}

extern "C" void kernel_launch(void* const* d_in, const int* in_sizes, int n_in,
                              void* d_out, int out_size, void* d_ws, size_t ws_size,
                              hipStream_t stream) {
    const float* x    = (const float*)d_in[0];
    const float* deg  = (const float*)d_in[1];
    const int*   eidx = (const int*)d_in[2];
    const int*   eatt = (const int*)d_in[3];
    const float* Wsrc = (const float*)d_in[4];
    const float* Wtgt = (const float*)d_in[5];
    const float* emb  = (const float*)d_in[6];
    const float* Wg   = (const float*)d_in[7];
    const float* Wv   = (const float*)d_in[8];
    const float* Wp   = (const float*)d_in[9];
    const float* dp   = (const float*)d_in[10];
    int N = in_sizes[0] / WID;
    int E = in_sizes[2] / 2;
    int BOND = in_sizes[6] / WID;

    float* ws     = (float*)d_ws;
    float* aggact = ws;
    int*   cnt    = (int*)(aggact + (size_t)N * WID);
    int*   cur    = cnt + N;
    int*   perm   = cur + N;
    unsigned short* xsb = (unsigned short*)(perm + E);
    unsigned short* xtb = xsb + (size_t)N * WID;
    unsigned short* Wpb = xtb + (size_t)N * WID;
    unsigned short* Wgb = Wpb + 65536;
    unsigned short* Wvb = Wgb + 8192;
    unsigned short* embWgT = Wvb + 8192;

    int PB = (N + 31) / 32;
    int AUX = 128;
    int NT = (E + 31) / 32;
    int PER = (NT + 7) / 8;

    hipMemsetAsync(cnt, 0, (size_t)N * sizeof(int), stream);
    prepproj_k<<<PB + AUX, 256, 0, stream>>>(x, Wsrc, Wtgt, Wp, Wg, Wv, emb, eidx,
                                             xsb, xtb, Wpb, Wgb, Wvb, embWgT, cnt, aggact,
                                             N, E, BOND, PB, AUX);
    scan_k<<<1, 1024, 0, stream>>>(cnt, cur, N);
    scat_k<<<(E + 255) / 256, 256, 0, stream>>>(eidx, cur, perm, E);
    edge_k<<<PER * 8, 256, 0, stream>>>(xsb, xtb, eidx, eatt, perm, Wgb, Wvb, embWgT,
                                        aggact, E, NT, PER);
    post_k<<<(N + 31) / 32, 256, 0, stream>>>(aggact, Wpb, deg, dp, (float*)d_out, N);
}

// Round 12
// 231.388 us; speedup vs baseline: 1.0652x; 1.0652x over previous
//
#include <hip/hip_runtime.h>

#define WID 256
#define EPS_GN 1e-5f

typedef __bf16 v8bf __attribute__((ext_vector_type(8)));
typedef __bf16 v2bf __attribute__((ext_vector_type(2)));
typedef float  v4f  __attribute__((ext_vector_type(4)));

__device__ inline unsigned short f2b(float f) {
    unsigned int u = __builtin_bit_cast(unsigned int, f);
    unsigned int r = (u + 0x7fffu + ((u >> 16) & 1u)) >> 16;
    return (unsigned short)r;
}
__device__ inline float lo16(unsigned int u) { return __builtin_bit_cast(float, u << 16); }
__device__ inline float hi16(unsigned int u) { return __builtin_bit_cast(float, u & 0xffff0000u); }

#if __has_builtin(__builtin_amdgcn_cvt_pk_bf16_f32)
__device__ inline unsigned int pkbf(float a, float b) {
    v2bf r = __builtin_amdgcn_cvt_pk_bf16_f32(a, b);
    return __builtin_bit_cast(unsigned int, r);
}
#else
__device__ inline unsigned int pkbf(float a, float b) {
    return (unsigned int)f2b(a) | ((unsigned int)f2b(b) << 16);
}
#endif

#if __has_builtin(__builtin_amdgcn_fdot2_f32_bf16)
__device__ inline float pairsum(unsigned int u, float s) {
    v2bf p = __builtin_bit_cast(v2bf, u);
    v2bf ones = __builtin_bit_cast(v2bf, 0x3f803f80u);
    return __builtin_amdgcn_fdot2_f32_bf16(p, ones, s, false);
}
#else
__device__ inline float pairsum(unsigned int u, float s) {
    return s + lo16(u) + hi16(u);
}
#endif

// ================= cast weights + zero cnt (replaces the memset launch) =================
__global__ void cast_k(const float* __restrict__ Wsrc, const float* __restrict__ Wtgt,
                       const float* __restrict__ Wp, const float* __restrict__ Wg,
                       const float* __restrict__ Wv, const float* __restrict__ emb,
                       unsigned short* __restrict__ Wsb, unsigned short* __restrict__ Wtb,
                       unsigned short* __restrict__ Wpb, unsigned short* __restrict__ Wgb,
                       unsigned short* __restrict__ Wvb, unsigned short* __restrict__ embWgT,
                       int* __restrict__ cnt, int N, int BOND) {
    int i = blockIdx.x * 256 + threadIdx.x;  // 320*256 = 81920 threads
    int gsz = gridDim.x * 256;
    for (int j = i; j < N; j += gsz) cnt[j] = 0;
    for (int j = i; j < 65536; j += gsz) {
        Wsb[j] = f2b(Wsrc[j]); Wtb[j] = f2b(Wtgt[j]); Wpb[j] = f2b(Wp[j]);
    }
    for (int j = i; j < 8192; j += gsz) { Wgb[j] = f2b(Wg[j]); Wvb[j] = f2b(Wv[j]); }
    for (int j = i; j < 16384; j += gsz) {
        int jr = j >> 6, k = j & 63;
        float sacc = 0.f;
        if (k < BOND) {
            int h = jr >> 5, f = jr & 31;
            const float* er = emb + (size_t)k * WID + h * 32;
            const float* wr = Wg + h * 1024 + f * 32;
#pragma unroll
            for (int d = 0; d < 32; d++) sacc += er[d] * wr[d];
        }
        embWgT[jr * 64 + k] = f2b(sacc);
    }
}

// ================= proj (bf16 weights) + aux (hist + zero aggact) =================
__global__ __launch_bounds__(256, 2)
void prepproj_k(const float* __restrict__ x, const unsigned short* __restrict__ Wsb,
                const unsigned short* __restrict__ Wtb, const int* __restrict__ eidx,
                unsigned short* __restrict__ xsb, unsigned short* __restrict__ xtb,
                int* __restrict__ cnt, float* __restrict__ aggact,
                int N, int E, int PB, int AUX) {
    __shared__ unsigned short ab[32 * 264];
    int t = threadIdx.x, b = blockIdx.x;

    if (b >= PB) {
        int atid = (b - PB) * 256 + t, asz = AUX * 256;
        {
            float4* ap = (float4*)aggact;
            int n4 = (N * WID) >> 2;
            for (int i = atid; i < n4; i += asz) ap[i] = make_float4(0.f, 0.f, 0.f, 0.f);
        }
        for (int i = atid; i < E; i += asz) atomicAdd(&cnt[eidx[E + i]], 1);
        return;
    }

    // ---- proj tile ----
    int n0 = b * 32;
#pragma unroll
    for (int ch = 0; ch < 8; ch++) {
        int flat = ch * 1024 + t * 4;
        int row = flat >> 8, col = flat & 255;
        int n = n0 + row;
        float4 v = (n < N) ? *(const float4*)&x[(size_t)n * WID + col]
                           : make_float4(0.f, 0.f, 0.f, 0.f);
        *(uint2*)&ab[row * 264 + col] = make_uint2(pkbf(v.x, v.y), pkbf(v.z, v.w));
    }
    __syncthreads();
    int w = t >> 6, lane = t & 63, m = lane & 15, kg = lane >> 4;
#pragma unroll
    for (int pass = 0; pass < 2; pass++) {
        const unsigned short* Wb = pass ? Wtb : Wsb;
        unsigned short* outp = pass ? xtb : xsb;
        v4f acc[2][4];
#pragma unroll
        for (int mt = 0; mt < 2; mt++)
#pragma unroll
            for (int nt = 0; nt < 4; nt++) acc[mt][nt] = (v4f){0.f, 0.f, 0.f, 0.f};
#pragma unroll
        for (int kt = 0; kt < 8; kt++) {
            int k0 = kt * 32 + kg * 8;
            v8bf a0 = *(const v8bf*)&ab[m * 264 + k0];
            v8bf a1 = *(const v8bf*)&ab[(16 + m) * 264 + k0];
#pragma unroll
            for (int nt = 0; nt < 4; nt++) {
                int j = w * 64 + nt * 16 + m;
                v8bf bfr = *(const v8bf*)&Wb[j * 256 + k0];
                acc[0][nt] = __builtin_amdgcn_mfma_f32_16x16x32_bf16(a0, bfr, acc[0][nt], 0, 0, 0);
                acc[1][nt] = __builtin_amdgcn_mfma_f32_16x16x32_bf16(a1, bfr, acc[1][nt], 0, 0, 0);
            }
        }
#pragma unroll
        for (int mt = 0; mt < 2; mt++)
#pragma unroll
            for (int r = 0; r < 4; r++) {
                int n = n0 + mt * 16 + kg * 4 + r;
                if (n < N)
#pragma unroll
                    for (int nt = 0; nt < 4; nt++)
                        outp[(size_t)n * WID + w * 64 + nt * 16 + m] = f2b(acc[mt][nt][r]);
            }
    }
}

// ================= exclusive scan (LDS-staged, coalesced) =================
__global__ void scan_k(const int* __restrict__ cnt, int* __restrict__ cur, int N) {
    __shared__ int buf[10240];
    __shared__ int part[1024];
    int t = threadIdx.x;
    int C = (N + 1023) >> 10;           // N <= 10240
    int M = C << 10;
    for (int i = t; i < M; i += 1024) buf[i] = (i < N) ? cnt[i] : 0;
    __syncthreads();
    int base0 = t * C;
    int s = 0;
    for (int i = 0; i < C; i++) s += buf[base0 + i];
    part[t] = s;
    __syncthreads();
    for (int d = 1; d < 1024; d <<= 1) {
        int v = (t >= d) ? part[t - d] : 0;
        __syncthreads();
        part[t] += v;
        __syncthreads();
    }
    int base = (t == 0) ? 0 : part[t - 1];
    for (int i = 0; i < C; i++) {
        int idx = base0 + i;
        int v = buf[idx];
        buf[idx] = base;
        base += v;
    }
    __syncthreads();
    for (int i = t; i < N; i += 1024) cur[i] = buf[i];
}

// ================= scatter perm =================
__global__ void scat_k(const int* __restrict__ eidx, int* __restrict__ cur,
                       int* __restrict__ perm, int E) {
    int i = blockIdx.x * 256 + threadIdx.x;
    if (i < E) { int p = atomicAdd(&cur[eidx[E + i]], 1); perm[p] = i; }
}

// ================= fused edge pipeline (R10 form — empirical best) =================
__global__ __launch_bounds__(256, 7)
void edge_k(const unsigned short* __restrict__ xsb, const unsigned short* __restrict__ xtb,
            const int* __restrict__ eidx, const int* __restrict__ eattr,
            const int* __restrict__ perm, const unsigned short* __restrict__ Wgb,
            const unsigned short* __restrict__ Wvb, const unsigned short* __restrict__ embWgT,
            float* __restrict__ aggact, int E, int NT, int PER) {
    __shared__ unsigned short xxb[8704];      // xn (32 x 264) -> act_t (256 x stride 34)
    __shared__ unsigned short Mld[32 * 72];
    __shared__ int src_s[32], tgt_s[32];
    __shared__ int segmask_s;

    // XCD-aware swizzle: each XCD (b&7) gets a contiguous range of sorted tiles
    int tile = (blockIdx.x & 7) * PER + (blockIdx.x >> 3);
    if (tile >= NT) return;
    int t = threadIdx.x;
    int e0 = tile * 32;
    int ne = min(32, E - e0);

    // init: indices, M rows, segment flush bitmask (wave 0)
    {
        int tgtv = -1;
        if (t < 32) {
            int p = (t < ne) ? perm[e0 + t] : -1;
            src_s[t] = (p >= 0) ? eidx[p] : 0;
            tgtv = (p >= 0) ? eidx[E + p] : -1;
            tgt_s[t] = (tgtv >= 0) ? tgtv : 0;
            int a0 = 0, a1 = 0, a2 = 0;
            if (p >= 0) {
                const int* ap = eattr + (size_t)p * 3;
                a0 = ap[0]; a1 = ap[1]; a2 = ap[2];
            }
            unsigned int* Mr = (unsigned int*)&Mld[t * 72];
#pragma unroll
            for (int q = 0; q < 32; q++) Mr[q] = 0;
            int c = (a0 != 0) + (a1 != 0) + (a2 != 0);
            float inv = (p >= 0 && c > 0) ? 1.f / (float)c : 0.f;
            float wa = inv * (float)(1 + (a1 == a0) + (a2 == a0));
            float wb = inv * (float)(1 + (a2 == a1));
            Mld[t * 72 + a0] = f2b(wa);
            if (a1 != a0) Mld[t * 72 + a1] = f2b(wb);
            if (a2 != a0 && a2 != a1) Mld[t * 72 + a2] = f2b(inv);
        }
        if (t < 64) {
            int nxt = __shfl_down(tgtv, 1);
            bool flag = (t < ne) && ((t == ne - 1) || (nxt != tgtv));
            unsigned long long bal = __ballot(flag);
            if (t == 0) segmask_s = (int)(unsigned int)bal;
        }
    }
    __syncthreads();

    // P1: gather + GN stats (4-lane butterfly) -> bf16 xn
    {
        int e = t >> 3, c = t & 7;
        int sn = src_s[e], g = tgt_s[e];
        bool live = (e < ne);
        const uint4* ps = (const uint4*)(xsb + (size_t)sn * WID);
        const uint4* pt = (const uint4*)(xtb + (size_t)g * WID);
        uint4 us[4], ut[4];
#pragma unroll
        for (int i = 0; i < 4; i++) { us[i] = ps[c + 8 * i]; ut[i] = pt[c + 8 * i]; }
        float v[4][8], sum[4], sq[4];
#pragma unroll
        for (int i = 0; i < 4; i++) {
            const unsigned int* au = (const unsigned int*)&us[i];
            const unsigned int* bu = (const unsigned int*)&ut[i];
            sum[i] = 0.f; sq[i] = 0.f;
#pragma unroll
            for (int q = 0; q < 4; q++) {
                float x0 = lo16(au[q]) + lo16(bu[q]);
                float x1 = hi16(au[q]) + hi16(bu[q]);
                if (!live) { x0 = 0.f; x1 = 0.f; }
                v[i][2 * q] = x0; v[i][2 * q + 1] = x1;
                sum[i] += x0 + x1;
                sq[i] += x0 * x0 + x1 * x1;
            }
        }
#pragma unroll
        for (int mask = 1; mask <= 2; mask <<= 1)
#pragma unroll
            for (int i = 0; i < 4; i++) {
                sum[i] += __shfl_xor(sum[i], mask);
                sq[i]  += __shfl_xor(sq[i], mask);
            }
#pragma unroll
        for (int i = 0; i < 4; i++) {
            float mu = sum[i] * (1.f / 32.f);
            float var = sq[i] * (1.f / 32.f) - mu * mu;
            float rs = rsqrtf(var + EPS_GN);
            float nmr = -mu * rs;
            unsigned int pk[4];
#pragma unroll
            for (int q = 0; q < 4; q++)
                pk[q] = pkbf(fmaf(v[i][2 * q], rs, nmr), fmaf(v[i][2 * q + 1], rs, nmr));
            *(uint4*)&xxb[e * 264 + (c + 8 * i) * 8] = make_uint4(pk[0], pk[1], pk[2], pk[3]);
        }
    }
    __syncthreads();

    // P5: gate/val MFMA -> act stored TRANSPOSED (act_t[col][e], stride 34), packed writes
    {
        int w = t >> 6, lane = t & 63, m = lane & 15, kg = lane >> 4;
        v8bf axn[2][2], aM[2][2];
#pragma unroll
        for (int mt = 0; mt < 2; mt++) {
            int row = mt * 16 + m;
            axn[0][mt] = *(const v8bf*)&xxb[row * 264 + (w * 2 + 0) * 32 + kg * 8];
            axn[1][mt] = *(const v8bf*)&xxb[row * 264 + (w * 2 + 1) * 32 + kg * 8];
            aM[mt][0] = *(const v8bf*)&Mld[row * 72 + kg * 8];
            aM[mt][1] = *(const v8bf*)&Mld[row * 72 + 32 + kg * 8];
        }
        __syncthreads();  // xn fully consumed before act_t overwrites xxb
        v4f z = {0.f, 0.f, 0.f, 0.f};
#pragma unroll
        for (int hh = 0; hh < 2; hh++) {
            int h = w * 2 + hh;
#pragma unroll
            for (int nt = 0; nt < 2; nt++) {
                int fj = nt * 16 + m;
                int j = h * 32 + fj;
                v8bf bWg = *(const v8bf*)&Wgb[h * 1024 + fj * 32 + kg * 8];
                v8bf bWv = *(const v8bf*)&Wvb[h * 1024 + fj * 32 + kg * 8];
                v8bf bE0 = *(const v8bf*)&embWgT[j * 64 + kg * 8];
                v8bf bE1 = *(const v8bf*)&embWgT[j * 64 + 32 + kg * 8];
#pragma unroll
                for (int mt = 0; mt < 2; mt++) {
                    v4f cgm = __builtin_amdgcn_mfma_f32_16x16x32_bf16(axn[hh][mt], bWg, z, 0, 0, 0);
                    cgm = __builtin_amdgcn_mfma_f32_16x16x32_bf16(aM[mt][0], bE0, cgm, 0, 0, 0);
                    cgm = __builtin_amdgcn_mfma_f32_16x16x32_bf16(aM[mt][1], bE1, cgm, 0, 0, 0);
                    v4f cv = __builtin_amdgcn_mfma_f32_16x16x32_bf16(axn[hh][mt], bWv, z, 0, 0, 0);
                    float a0 = fmaxf(cgm[0], 0.f) * cv[0];
                    float a1 = fmaxf(cgm[1], 0.f) * cv[1];
                    float a2 = fmaxf(cgm[2], 0.f) * cv[2];
                    float a3 = fmaxf(cgm[3], 0.f) * cv[3];
                    int e0i = mt * 16 + kg * 4;  // even -> uint-aligned
                    *(unsigned int*)&xxb[j * 34 + e0i]     = pkbf(a0, a1);
                    *(unsigned int*)&xxb[j * 34 + e0i + 2] = pkbf(a2, a3);
                }
            }
        }
    }
    __syncthreads();

    // P6: segmented column reduce; packed pair-sums, scalar bit-test flushes
    {
        unsigned int mask = (unsigned int)__builtin_amdgcn_readfirstlane(segmask_s);
        float sum = 0.f;
#pragma unroll
        for (int i = 0; i < 16; i++) {
            unsigned int r = *(const unsigned int*)&xxb[t * 34 + 2 * i];
            if (!((mask >> (2 * i)) & 1)) {
                sum = pairsum(r, sum);
                if ((mask >> (2 * i + 1)) & 1) {
                    int tg = __builtin_amdgcn_readfirstlane(tgt_s[2 * i + 1]);
                    atomicAdd(&aggact[(size_t)tg * WID + t], sum);
                    sum = 0.f;
                }
            } else {
                sum += lo16(r);
                int tg = __builtin_amdgcn_readfirstlane(tgt_s[2 * i]);
                atomicAdd(&aggact[(size_t)tg * WID + t], sum);
                sum = hi16(r);
                if ((mask >> (2 * i + 1)) & 1) {
                    int tg2 = __builtin_amdgcn_readfirstlane(tgt_s[2 * i + 1]);
                    atomicAdd(&aggact[(size_t)tg2 * WID + t], sum);
                    sum = 0.f;
                }
            }
        }
    }
}

// ================= post: out = deg^p ⊙ (aggact @ Wp^T) =================
__global__ __launch_bounds__(256, 2)
void post_k(const float* __restrict__ aggact, const unsigned short* __restrict__ Wpb,
            const float* __restrict__ deg, const float* __restrict__ dp,
            float* __restrict__ out, int N) {
    __shared__ unsigned short ab[32 * 264];
    __shared__ float degl[32];
    int t = threadIdx.x;
    int n0 = blockIdx.x * 32;
#pragma unroll
    for (int ch = 0; ch < 8; ch++) {
        int flat = ch * 1024 + t * 4;
        int row = flat >> 8, col = flat & 255;
        int n = n0 + row;
        float4 v = (n < N) ? *(const float4*)&aggact[(size_t)n * WID + col]
                           : make_float4(0.f, 0.f, 0.f, 0.f);
        *(uint2*)&ab[row * 264 + col] = make_uint2(pkbf(v.x, v.y), pkbf(v.z, v.w));
    }
    if (t < 32) {
        int n = n0 + t;
        degl[t] = (n < N) ? log2f(deg[n]) : 0.f;
    }
    __syncthreads();
    int w = t >> 6, lane = t & 63, m = lane & 15, kg = lane >> 4;
    v4f acc[2][4];
#pragma unroll
    for (int mt = 0; mt < 2; mt++)
#pragma unroll
        for (int nt = 0; nt < 4; nt++) acc[mt][nt] = (v4f){0.f, 0.f, 0.f, 0.f};
#pragma unroll
    for (int kt = 0; kt < 8; kt++) {
        int k0 = kt * 32 + kg * 8;
        v8bf a0 = *(const v8bf*)&ab[m * 264 + k0];
        v8bf a1 = *(const v8bf*)&ab[(16 + m) * 264 + k0];
#pragma unroll
        for (int nt = 0; nt < 4; nt++) {
            int j = w * 64 + nt * 16 + m;
            v8bf b = *(const v8bf*)&Wpb[j * 256 + k0];
            acc[0][nt] = __builtin_amdgcn_mfma_f32_16x16x32_bf16(a0, b, acc[0][nt], 0, 0, 0);
            acc[1][nt] = __builtin_amdgcn_mfma_f32_16x16x32_bf16(a1, b, acc[1][nt], 0, 0, 0);
        }
    }
    float dpv[4];
#pragma unroll
    for (int nt = 0; nt < 4; nt++) dpv[nt] = dp[w * 64 + nt * 16 + m];
#pragma unroll
    for (int mt = 0; mt < 2; mt++)
#pragma unroll
        for (int r = 0; r < 4; r++) {
            int row = mt * 16 + kg * 4 + r;
            int n = n0 + row;
            if (n < N) {
                float ld = degl[row];
#pragma unroll
                for (int nt = 0; nt < 4; nt++)
                    out[(size_t)n * WID + w * 64 + nt * 16 + m] =
                        exp2f(dpv[nt] * ld) * acc[mt][nt][r];
            }
        }
}

extern "C" void kernel_launch(void* const* d_in, const int* in_sizes, int n_in,
                              void* d_out, int out_size, void* d_ws, size_t ws_size,
                              hipStream_t stream) {
    const float* x    = (const float*)d_in[0];
    const float* deg  = (const float*)d_in[1];
    const int*   eidx = (const int*)d_in[2];
    const int*   eatt = (const int*)d_in[3];
    const float* Wsrc = (const float*)d_in[4];
    const float* Wtgt = (const float*)d_in[5];
    const float* emb  = (const float*)d_in[6];
    const float* Wg   = (const float*)d_in[7];
    const float* Wv   = (const float*)d_in[8];
    const float* Wp   = (const float*)d_in[9];
    const float* dp   = (const float*)d_in[10];
    int N = in_sizes[0] / WID;
    int E = in_sizes[2] / 2;
    int BOND = in_sizes[6] / WID;

    float* ws     = (float*)d_ws;
    float* aggact = ws;
    int*   cnt    = (int*)(aggact + (size_t)N * WID);
    int*   cur    = cnt + N;
    int*   perm   = cur + N;
    unsigned short* xsb = (unsigned short*)(perm + E);
    unsigned short* xtb = xsb + (size_t)N * WID;
    unsigned short* Wsb = xtb + (size_t)N * WID;
    unsigned short* Wtb = Wsb + 65536;
    unsigned short* Wpb = Wtb + 65536;
    unsigned short* Wgb = Wpb + 65536;
    unsigned short* Wvb = Wgb + 8192;
    unsigned short* embWgT = Wvb + 8192;

    int PB = (N + 31) / 32;
    int AUX = 128;
    int NT = (E + 31) / 32;
    int PER = (NT + 7) / 8;

    cast_k<<<320, 256, 0, stream>>>(Wsrc, Wtgt, Wp, Wg, Wv, emb,
                                    Wsb, Wtb, Wpb, Wgb, Wvb, embWgT, cnt, N, BOND);
    prepproj_k<<<PB + AUX, 256, 0, stream>>>(x, Wsb, Wtb, eidx, xsb, xtb, cnt, aggact,
                                             N, E, PB, AUX);
    scan_k<<<1, 1024, 0, stream>>>(cnt, cur, N);
    scat_k<<<(E + 255) / 256, 256, 0, stream>>>(eidx, cur, perm, E);
    edge_k<<<PER * 8, 256, 0, stream>>>(xsb, xtb, eidx, eatt, perm, Wgb, Wvb, embWgT,
                                        aggact, E, NT, PER);
    post_k<<<(N + 31) / 32, 256, 0, stream>>>(aggact, Wpb, deg, dp, (float*)d_out, N);
}